// Round 3
// baseline (566.218 us; speedup 1.0000x reference)
//
#include <hip/hip_runtime.h>

// ---------- types ----------
typedef __bf16 bf16x8 __attribute__((ext_vector_type(8)));
typedef float  f32x4  __attribute__((ext_vector_type(4)));
typedef unsigned short u16;
typedef u16 u16x8 __attribute__((ext_vector_type(8)));

#define MFMA16(a, b, c) __builtin_amdgcn_mfma_f32_16x16x32_bf16((a), (b), (c), 0, 0, 0)

__device__ __forceinline__ u16 f2bf(float f) {
    union { float f; unsigned u; } x; x.f = f;
    unsigned r = x.u + 0x7fffu + ((x.u >> 16) & 1u);
    return (u16)(r >> 16);
}

__device__ __forceinline__ void gll16(const void* g, void* l) {
    __builtin_amdgcn_global_load_lds(
        (const __attribute__((address_space(1))) void*)g,
        (__attribute__((address_space(3))) void*)l, 16, 0, 0);
}

// ---------- constants ----------
// B=4, T=2048, D=1024, H=16, dh=64, M=B*T=8192

// ---------- fp32 -> bf16 convert ----------
__global__ __launch_bounds__(256) void cvt_kernel(const float* __restrict__ in,
                                                  u16* __restrict__ out, int n4) {
    int i = blockIdx.x * 256 + threadIdx.x;
    if (i < n4) {
        float4 v = ((const float4*)in)[i];
        ushort4 o;
        o.x = f2bf(v.x); o.y = f2bf(v.y); o.z = f2bf(v.z); o.w = f2bf(v.w);
        ((ushort4*)out)[i] = o;
    }
}

// ---------- V transpose: v (B,H,T,64) -> vT (B,H,64,T) ----------
__global__ __launch_bounds__(256) void vtrans_kernel(const u16* __restrict__ v,
                                                     u16* __restrict__ vt) {
    __shared__ u16 Ls[64][72];
    const int bh = blockIdx.y;
    const int jt = blockIdx.x;
    const int tid = threadIdx.x;
    const u16* src = v + ((size_t)bh * 2048 + jt * 64) * 64;
#pragma unroll
    for (int p = 0; p < 2; p++) {
        int idx = p * 256 + tid;
        int r = idx >> 3, c0 = (idx & 7) * 8;
        *(u16x8*)&Ls[r][c0] = *(const u16x8*)(src + r * 64 + c0);
    }
    __syncthreads();
    u16* dst = vt + (size_t)bh * 64 * 2048 + jt * 64;
#pragma unroll
    for (int p = 0; p < 2; p++) {
        int idx = p * 256 + tid;
        int d = idx >> 3, t0 = (idx & 7) * 8;
        u16x8 o;
#pragma unroll
        for (int i = 0; i < 8; i++) o[i] = Ls[t0 + i][d];
        *(u16x8*)(dst + (size_t)d * 2048 + t0) = o;
    }
}

// ---------- GEMM: C = A @ Bm^T + bias ----------
template <int MODE>
__global__ __launch_bounds__(256) void gemm_bt(const u16* __restrict__ A,
                                               const u16* __restrict__ Bm,
                                               const float* __restrict__ b0,
                                               const float* __restrict__ b1,
                                               const float* __restrict__ b2,
                                               u16* __restrict__ qo,
                                               u16* __restrict__ ko,
                                               u16* __restrict__ vo,
                                               float* __restrict__ outp) {
    __shared__ u16 As[128 * 32];
    __shared__ u16 Bs[128 * 32];
    const int tid = threadIdx.x;
    const int w = tid >> 6, l = tid & 63;
    const int wr = w >> 1, wc = w & 1;
    const int lr = l & 15, lg = l >> 4;
    const int m0 = blockIdx.y * 128, n0 = blockIdx.x * 128;

    f32x4 acc[4][4];
#pragma unroll
    for (int i = 0; i < 4; i++)
#pragma unroll
        for (int j = 0; j < 4; j++) acc[i][j] = (f32x4){0.f, 0.f, 0.f, 0.f};

    const int srow = tid >> 2;
    const int scol = (tid & 3) * 8;

    for (int kk0 = 0; kk0 < 1024; kk0 += 32) {
        const u16* ag = A + (size_t)(m0 + srow) * 1024 + kk0 + scol;
        gll16(ag, As + tid * 8);
        gll16(ag + (size_t)64 * 1024, As + 2048 + tid * 8);
        const u16* bg = Bm + (size_t)(n0 + srow) * 1024 + kk0 + scol;
        gll16(bg, Bs + tid * 8);
        gll16(bg + (size_t)64 * 1024, Bs + 2048 + tid * 8);
        __syncthreads();

        bf16x8 af[4], bfb[4];
#pragma unroll
        for (int mi = 0; mi < 4; mi++)
            af[mi] = *(const bf16x8*)&As[(wr * 64 + mi * 16 + lr) * 32 + lg * 8];
#pragma unroll
        for (int ni = 0; ni < 4; ni++)
            bfb[ni] = *(const bf16x8*)&Bs[(wc * 64 + ni * 16 + lr) * 32 + lg * 8];
#pragma unroll
        for (int mi = 0; mi < 4; mi++)
#pragma unroll
            for (int ni = 0; ni < 4; ni++)
                acc[mi][ni] = MFMA16(af[mi], bfb[ni], acc[mi][ni]);
        __syncthreads();
    }

#pragma unroll
    for (int mi = 0; mi < 4; mi++) {
#pragma unroll
        for (int ni = 0; ni < 4; ni++) {
            const int ng = n0 + wc * 64 + ni * 16 + lr;
#pragma unroll
            for (int jj = 0; jj < 4; jj++) {
                const int mg = m0 + wr * 64 + mi * 16 + lg * 4 + jj;
                float val = acc[mi][ni][jj];
                if (MODE == 0) {
                    const int which = ng >> 10;
                    const int nn = ng & 1023;
                    const float* bsel = (which == 0) ? b0 : (which == 1) ? b1 : b2;
                    val += bsel[nn];
                    const int hh = nn >> 6, dc = nn & 63;
                    const int bb = mg >> 11, tt = mg & 2047;
                    u16* dst = (which == 0) ? qo : (which == 1) ? ko : vo;
                    dst[(((size_t)(bb * 16 + hh)) * 2048 + tt) * 64 + dc] = f2bf(val);
                } else {
                    val += b0[ng];
                    outp[(size_t)mg * 1024 + ng] = val;
                }
            }
        }
    }
}

// ---------- flash attention (barrier-free, L2-streaming K/V) ----------
// q,k: bf16 (B,H,T,64); vt: bf16 (B,H,64,T); out ao: bf16 (B,T,1024)
// Each wave independently computes 16 q-rows. K/V B-fragments are read
// directly from global (L2/L3-hot; K tile reused by 32 q-blocks). Only P
// round-trips through per-wave LDS (2KB each), guarded by lgkmcnt waits.
__global__ __launch_bounds__(256) void attn_kernel(const u16* __restrict__ q,
                                                   const u16* __restrict__ k,
                                                   const u16* __restrict__ vt,
                                                   u16* __restrict__ ao) {
    __shared__ u16 Ps[4][1024];

    const int qt = blockIdx.x;   // 0..31
    const int bh = blockIdx.y;   // 0..63
    const int b = bh >> 4, h = bh & 15;
    const int tid = threadIdx.x;
    const int w = tid >> 6, l = tid & 63;
    const int lr = l & 15, lg = l >> 4;

    const u16* qb = q + (size_t)bh * 2048 * 64;
    const u16* kb = k + (size_t)bh * 2048 * 64;
    const u16* vtb = vt + (size_t)bh * 64 * 2048;

    // Q fragments (A layout: row = lane&15, k-frag = (lane>>4)*8), d 0..31 / 32..63
    bf16x8 qf[2];
    {
        const int row = qt * 64 + w * 16 + lr;
        qf[0] = *(const bf16x8*)(qb + (size_t)row * 64 + lg * 8);
        qf[1] = *(const bf16x8*)(qb + (size_t)row * 64 + 32 + lg * 8);
    }

    float m_[4], lsum[4];
    f32x4 acc[4];
#pragma unroll
    for (int j = 0; j < 4; j++) {
        m_[j] = -INFINITY; lsum[j] = 0.f;
        acc[j] = (f32x4){0.f, 0.f, 0.f, 0.f};
    }

    // per-thread global offsets for K and Vt fragment loads
    const size_t koff0 = (size_t)lr * 64 + lg * 8;        // + nb*16*64 + jt*4096
    const size_t voff0 = (size_t)lr * 2048 + lg * 8;      // + nb*16*2048 + jt*64 + kb2*32

    for (int jt = 0; jt <= qt; ++jt) {
        const u16* kt = kb + (size_t)jt * 4096;

        // ---- K fragments from global (coalesced b128, L2-hot) ----
        bf16x8 bk0[4], bk1[4];
#pragma unroll
        for (int nb = 0; nb < 4; ++nb) {
            bk0[nb] = *(const bf16x8*)(kt + koff0 + (size_t)nb * 1024);
            bk1[nb] = *(const bf16x8*)(kt + koff0 + (size_t)nb * 1024 + 32);
        }

        // ---- V fragments from global (issued early, consumed after softmax) ----
        bf16x8 vf[2][4];
#pragma unroll
        for (int kb2 = 0; kb2 < 2; ++kb2)
#pragma unroll
            for (int nb = 0; nb < 4; ++nb)
                vf[kb2][nb] = *(const bf16x8*)(vtb + voff0 + (size_t)nb * 16 * 2048
                                               + jt * 64 + kb2 * 32);

        // ---- S = Q K^T (per wave: 16 q-rows x 64 keys) ----
        f32x4 sf[4];
#pragma unroll
        for (int nb = 0; nb < 4; ++nb) {
            f32x4 s = (f32x4){0.f, 0.f, 0.f, 0.f};
            s = MFMA16(qf[0], bk0[nb], s);
            s = MFMA16(qf[1], bk1[nb], s);
            sf[nb] = s;
        }

        // ---- scale + (diagonal-only) causal mask + online softmax ----
        const bool diag = (jt == qt);
        const int qrow0 = w * 16 + lg * 4;
#pragma unroll
        for (int jj = 0; jj < 4; jj++) {
            if (diag) {
#pragma unroll
                for (int nb = 0; nb < 4; nb++) {
                    float sv = sf[nb][jj] * 0.125f;
                    if (lr + nb * 16 > qrow0 + jj) sv = -INFINITY;
                    sf[nb][jj] = sv;
                }
            } else {
#pragma unroll
                for (int nb = 0; nb < 4; nb++) sf[nb][jj] *= 0.125f;
            }
            float mx = fmaxf(fmaxf(sf[0][jj], sf[1][jj]), fmaxf(sf[2][jj], sf[3][jj]));
#pragma unroll
            for (int d = 1; d < 16; d <<= 1) mx = fmaxf(mx, __shfl_xor(mx, d));
            const float mnew = fmaxf(m_[jj], mx);
            const float sc = __expf(m_[jj] - mnew);
            m_[jj] = mnew;
            lsum[jj] *= sc;
            acc[0][jj] *= sc; acc[1][jj] *= sc; acc[2][jj] *= sc; acc[3][jj] *= sc;
            float ps = 0.f;
#pragma unroll
            for (int nb = 0; nb < 4; nb++) {
                float p = __expf(sf[nb][jj] - mnew);
                sf[nb][jj] = p;
                ps += p;
            }
#pragma unroll
            for (int d = 1; d < 16; d <<= 1) ps += __shfl_xor(ps, d);
            lsum[jj] += ps;
        }

        // ---- write P (per-wave LDS region, swizzled) ----
        u16* Pw = &Ps[w][0];
        // ensure prior PV reads of Pw have completed before overwrite
        asm volatile("s_waitcnt lgkmcnt(0)" ::: "memory");
#pragma unroll
        for (int nb = 0; nb < 4; nb++)
#pragma unroll
            for (int jj = 0; jj < 4; jj++) {
                const int row = lg * 4 + jj;
                const int e = row * 64 + nb * 16 + lr;
                Pw[e ^ ((row & 7) << 3)] = f2bf(sf[nb][jj]);
            }
        asm volatile("s_waitcnt lgkmcnt(0)" ::: "memory");
        __builtin_amdgcn_sched_barrier(0);

        // ---- O += P V ----
#pragma unroll
        for (int kb2 = 0; kb2 < 2; ++kb2) {
            const int ep = lr * 64 + kb2 * 32 + lg * 8;
            bf16x8 pa = *(const bf16x8*)&Pw[ep ^ ((lr & 7) << 3)];
#pragma unroll
            for (int nb = 0; nb < 4; nb++)
                acc[nb] = MFMA16(pa, vf[kb2][nb], acc[nb]);
        }
    }

    // ---- epilogue: normalize, store to (B,T,1024) bf16 ----
    const int trow = qt * 64 + w * 16 + lg * 4;
    u16* aob = ao + ((size_t)b * 2048) * 1024 + h * 64;
#pragma unroll
    for (int jj = 0; jj < 4; jj++) {
        const float inv = 1.0f / lsum[jj];
#pragma unroll
        for (int nb = 0; nb < 4; nb++)
            aob[(size_t)(trow + jj) * 1024 + nb * 16 + lr] = f2bf(acc[nb][jj] * inv);
    }
}

// ---------- launch ----------
extern "C" void kernel_launch(void* const* d_in, const int* in_sizes, int n_in,
                              void* d_out, int out_size, void* d_ws, size_t ws_size,
                              hipStream_t stream) {
    const float* x  = (const float*)d_in[0];
    const float* Wq = (const float*)d_in[2];
    const float* bq = (const float*)d_in[3];
    const float* Wk = (const float*)d_in[4];
    const float* bk = (const float*)d_in[5];
    const float* Wv = (const float*)d_in[6];
    const float* bv = (const float*)d_in[7];
    const float* Wo = (const float*)d_in[8];
    const float* bo = (const float*)d_in[9];
    float* out = (float*)d_out;

    const size_t MD = (size_t)8192 * 1024;
    u16* xb   = (u16*)d_ws;                 // x bf16; reused as vT after projections
    u16* wqkv = xb + MD;
    u16* wo   = wqkv + 3 * 1024 * 1024;
    u16* qw   = wo + 1024 * 1024;           // (B,H,T,64)
    u16* kw   = qw + MD;
    u16* vw   = kw + MD;                    // (B,H,T,64); reused as ao after transpose
    u16* vtw  = xb;                          // (B,H,64,T)
    u16* ao   = vw;                          // (B,T,1024)

    cvt_kernel<<<8192, 256, 0, stream>>>(x, xb, (int)(MD / 4));
    cvt_kernel<<<1024, 256, 0, stream>>>(Wq, wqkv, 262144);
    cvt_kernel<<<1024, 256, 0, stream>>>(Wk, wqkv + 1024 * 1024, 262144);
    cvt_kernel<<<1024, 256, 0, stream>>>(Wv, wqkv + 2 * 1024 * 1024, 262144);
    cvt_kernel<<<1024, 256, 0, stream>>>(Wo, wo, 262144);

    // QKV projection
    gemm_bt<0><<<dim3(24, 64), 256, 0, stream>>>(xb, wqkv, bq, bk, bv,
                                                 qw, kw, vw, nullptr);

    // transpose V: (B,H,T,64) -> (B,H,64,T)
    vtrans_kernel<<<dim3(32, 64), 256, 0, stream>>>(vw, vtw);

    // flash attention -> ao
    attn_kernel<<<dim3(32, 64), 256, 0, stream>>>(qw, kw, vtw, ao);

    // output projection
    gemm_bt<1><<<dim3(8, 64), 256, 0, stream>>>(ao, wo, bo, bo, bo,
                                                nullptr, nullptr, nullptr, out);
}

// Round 4
// 264.995 us; speedup vs baseline: 2.1367x; 2.1367x over previous
//
#include <hip/hip_runtime.h>

// ---------- types ----------
typedef __bf16 bf16x8 __attribute__((ext_vector_type(8)));
typedef float  f32x4  __attribute__((ext_vector_type(4)));
typedef unsigned short u16;
typedef u16 u16x8 __attribute__((ext_vector_type(8)));

#define MFMA16(a, b, c) __builtin_amdgcn_mfma_f32_16x16x32_bf16((a), (b), (c), 0, 0, 0)

__device__ __forceinline__ u16 f2bf(float f) {
    union { float f; unsigned u; } x; x.f = f;
    unsigned r = x.u + 0x7fffu + ((x.u >> 16) & 1u);
    return (u16)(r >> 16);
}

__device__ __forceinline__ void gll16(const void* g, void* l) {
    __builtin_amdgcn_global_load_lds(
        (const __attribute__((address_space(1))) void*)g,
        (__attribute__((address_space(3))) void*)l, 16, 0, 0);
}

// ---------- constants ----------
// B=4, T=2048, D=1024, H=16, dh=64, M=B*T=8192

// ---------- fp32 -> bf16 convert ----------
__global__ __launch_bounds__(256) void cvt_kernel(const float* __restrict__ in,
                                                  u16* __restrict__ out, int n4) {
    int i = blockIdx.x * 256 + threadIdx.x;
    if (i < n4) {
        float4 v = ((const float4*)in)[i];
        ushort4 o;
        o.x = f2bf(v.x); o.y = f2bf(v.y); o.z = f2bf(v.z); o.w = f2bf(v.w);
        ((ushort4*)out)[i] = o;
    }
}

// ---------- V transpose: v (B,H,T,64) -> vT (B,H,64,T) ----------
__global__ __launch_bounds__(256) void vtrans_kernel(const u16* __restrict__ v,
                                                     u16* __restrict__ vt) {
    __shared__ u16 Ls[64][72];
    const int bh = blockIdx.y;
    const int jt = blockIdx.x;
    const int tid = threadIdx.x;
    const u16* src = v + ((size_t)bh * 2048 + jt * 64) * 64;
#pragma unroll
    for (int p = 0; p < 2; p++) {
        int idx = p * 256 + tid;
        int r = idx >> 3, c0 = (idx & 7) * 8;
        *(u16x8*)&Ls[r][c0] = *(const u16x8*)(src + r * 64 + c0);
    }
    __syncthreads();
    u16* dst = vt + (size_t)bh * 64 * 2048 + jt * 64;
#pragma unroll
    for (int p = 0; p < 2; p++) {
        int idx = p * 256 + tid;
        int d = idx >> 3, t0 = (idx & 7) * 8;
        u16x8 o;
#pragma unroll
        for (int i = 0; i < 8; i++) o[i] = Ls[t0 + i][d];
        *(u16x8*)(dst + (size_t)d * 2048 + t0) = o;
    }
}

// ---------- GEMM: C = A @ Bm^T + bias ----------
template <int MODE>
__global__ __launch_bounds__(256) void gemm_bt(const u16* __restrict__ A,
                                               const u16* __restrict__ Bm,
                                               const float* __restrict__ b0,
                                               const float* __restrict__ b1,
                                               const float* __restrict__ b2,
                                               u16* __restrict__ qo,
                                               u16* __restrict__ ko,
                                               u16* __restrict__ vo,
                                               float* __restrict__ outp) {
    __shared__ u16 As[128 * 32];
    __shared__ u16 Bs[128 * 32];
    const int tid = threadIdx.x;
    const int w = tid >> 6, l = tid & 63;
    const int wr = w >> 1, wc = w & 1;
    const int lr = l & 15, lg = l >> 4;
    const int m0 = blockIdx.y * 128, n0 = blockIdx.x * 128;

    f32x4 acc[4][4];
#pragma unroll
    for (int i = 0; i < 4; i++)
#pragma unroll
        for (int j = 0; j < 4; j++) acc[i][j] = (f32x4){0.f, 0.f, 0.f, 0.f};

    const int srow = tid >> 2;
    const int scol = (tid & 3) * 8;

    for (int kk0 = 0; kk0 < 1024; kk0 += 32) {
        const u16* ag = A + (size_t)(m0 + srow) * 1024 + kk0 + scol;
        gll16(ag, As + tid * 8);
        gll16(ag + (size_t)64 * 1024, As + 2048 + tid * 8);
        const u16* bg = Bm + (size_t)(n0 + srow) * 1024 + kk0 + scol;
        gll16(bg, Bs + tid * 8);
        gll16(bg + (size_t)64 * 1024, Bs + 2048 + tid * 8);
        __syncthreads();

        bf16x8 af[4], bfb[4];
#pragma unroll
        for (int mi = 0; mi < 4; mi++)
            af[mi] = *(const bf16x8*)&As[(wr * 64 + mi * 16 + lr) * 32 + lg * 8];
#pragma unroll
        for (int ni = 0; ni < 4; ni++)
            bfb[ni] = *(const bf16x8*)&Bs[(wc * 64 + ni * 16 + lr) * 32 + lg * 8];
#pragma unroll
        for (int mi = 0; mi < 4; mi++)
#pragma unroll
            for (int ni = 0; ni < 4; ni++)
                acc[mi][ni] = MFMA16(af[mi], bfb[ni], acc[mi][ni]);
        __syncthreads();
    }

#pragma unroll
    for (int mi = 0; mi < 4; mi++) {
#pragma unroll
        for (int ni = 0; ni < 4; ni++) {
            const int ng = n0 + wc * 64 + ni * 16 + lr;
#pragma unroll
            for (int jj = 0; jj < 4; jj++) {
                const int mg = m0 + wr * 64 + mi * 16 + lg * 4 + jj;
                float val = acc[mi][ni][jj];
                if (MODE == 0) {
                    const int which = ng >> 10;
                    const int nn = ng & 1023;
                    const float* bsel = (which == 0) ? b0 : (which == 1) ? b1 : b2;
                    val += bsel[nn];
                    const int hh = nn >> 6, dc = nn & 63;
                    const int bb = mg >> 11, tt = mg & 2047;
                    u16* dst = (which == 0) ? qo : (which == 1) ? ko : vo;
                    dst[(((size_t)(bb * 16 + hh)) * 2048 + tt) * 64 + dc] = f2bf(val);
                } else {
                    val += b0[ng];
                    outp[(size_t)mg * 1024 + ng] = val;
                }
            }
        }
    }
}

// ---------- flash attention (8-wave, 128 q-rows/block, staged K/V) ----------
// q,k: bf16 (B,H,T,64); vt: bf16 (B,H,64,T); out ao: bf16 (B,T,1024)
// 8 waves each own 16 q-rows; K/V 64-key tiles staged via global_load_lds
// (swizzled per rule 21), double-buffered, one barrier per tile. P goes
// through per-wave LDS with lgkmcnt discipline. bh is XCD-grouped so each
// XCD's 8 heads' K/V stay L2-resident.
__global__ __launch_bounds__(512) void attn_kernel(const u16* __restrict__ q,
                                                   const u16* __restrict__ k,
                                                   const u16* __restrict__ vt,
                                                   u16* __restrict__ ao) {
    __shared__ u16 Ks[2][4096];
    __shared__ u16 Vs[2][4096];
    __shared__ u16 Ps[8][1024];

    const int idx = blockIdx.x;              // 0..1023
    const int j = idx & 63;
    const int bh = ((j & 7) << 3) | (j >> 3); // XCD idx%8 -> bh group of 8
    const int qt = idx >> 6;                  // 0..15 (128-row q-tile)
    const int b = bh >> 4, h = bh & 15;
    const int tid = threadIdx.x;
    const int w = tid >> 6, l = tid & 63;
    const int lr = l & 15, lg = l >> 4;

    const u16* qb = q + (size_t)bh * 2048 * 64;
    const u16* kb = k + (size_t)bh * 2048 * 64;
    const u16* vtb = vt + (size_t)bh * 64 * 2048;

    const int r0 = qt * 128 + w * 16;        // wave's first q-row

    // Q fragments (A layout: row = lane&15, k-frag = (lane>>4)*8)
    bf16x8 qf[2];
    {
        const int row = r0 + lr;
        qf[0] = *(const bf16x8*)(qb + (size_t)row * 64 + lg * 8);
        qf[1] = *(const bf16x8*)(qb + (size_t)row * 64 + 32 + lg * 8);
    }

    // staging offsets (inverse-swizzled global source, linear LDS dest)
    const int u = tid;                        // 0..511, one gll16 for K + one for V
    const int ke = (u * 8) ^ (((u >> 3) & 7) << 3);
    const int vd = u >> 3, vc = ((u & 7) * 8) ^ ((vd & 7) << 3);

    float m_[4], lsum[4];
    f32x4 acc[4];
#pragma unroll
    for (int jj = 0; jj < 4; jj++) {
        m_[jj] = -INFINITY; lsum[jj] = 0.f;
        acc[jj] = (f32x4){0.f, 0.f, 0.f, 0.f};
    }

    const int nt = 2 * qt + 2;                // K-tiles covering rows < 128(qt+1)

    // prologue: stage tile 0 into buffer 0
    gll16(kb + ke, &Ks[0][0] + u * 8);
    gll16(vtb + (size_t)vd * 2048 + vc, &Vs[0][0] + u * 8);

    int cur = 0;
    for (int jt = 0; jt < nt; ++jt) {
        __syncthreads();   // buf[cur] staged; buf[cur^1] free

        if (jt + 1 < nt) { // prefetch next tile
            const int nxt = cur ^ 1;
            gll16(kb + (size_t)(jt + 1) * 4096 + ke, &Ks[nxt][0] + u * 8);
            gll16(vtb + (size_t)vd * 2048 + (jt + 1) * 64 + vc, &Vs[nxt][0] + u * 8);
        }

        const int k0 = jt * 64;
        if (k0 <= r0 + 15) {   // wave has unmasked work (wave-uniform branch)
            // ---- S = Q K^T ----
            f32x4 sf[4];
#pragma unroll
            for (int nb = 0; nb < 4; ++nb) {
                const int e0 = (nb * 16 + lr) * 64 + lg * 8;
                const int sx = (lr & 7) << 3;
                bf16x8 bk0 = *(const bf16x8*)&Ks[cur][e0 ^ sx];
                bf16x8 bk1 = *(const bf16x8*)&Ks[cur][(e0 + 32) ^ sx];
                f32x4 s = (f32x4){0.f, 0.f, 0.f, 0.f};
                s = MFMA16(qf[0], bk0, s);
                s = MFMA16(qf[1], bk1, s);
                sf[nb] = s;
            }

            // ---- scale + causal mask + online softmax ----
            const bool needmask = (k0 + 63 > r0);
            const int d0 = r0 + lg * 4 - k0 - lr;   // mask iff nb*16 > d0 + jj
#pragma unroll
            for (int jj = 0; jj < 4; jj++) {
                if (needmask) {
#pragma unroll
                    for (int nb = 0; nb < 4; nb++) {
                        float sv = sf[nb][jj] * 0.125f;
                        if (nb * 16 > d0 + jj) sv = -INFINITY;
                        sf[nb][jj] = sv;
                    }
                } else {
#pragma unroll
                    for (int nb = 0; nb < 4; nb++) sf[nb][jj] *= 0.125f;
                }
                float mx = fmaxf(fmaxf(sf[0][jj], sf[1][jj]), fmaxf(sf[2][jj], sf[3][jj]));
#pragma unroll
                for (int d = 1; d < 16; d <<= 1) mx = fmaxf(mx, __shfl_xor(mx, d));
                const float mnew = fmaxf(m_[jj], mx);
                const float sc = __expf(m_[jj] - mnew);
                m_[jj] = mnew;
                lsum[jj] *= sc;
                acc[0][jj] *= sc; acc[1][jj] *= sc; acc[2][jj] *= sc; acc[3][jj] *= sc;
                float ps = 0.f;
#pragma unroll
                for (int nb = 0; nb < 4; nb++) {
                    float p = __expf(sf[nb][jj] - mnew);
                    sf[nb][jj] = p;
                    ps += p;
                }
#pragma unroll
                for (int d = 1; d < 16; d <<= 1) ps += __shfl_xor(ps, d);
                lsum[jj] += ps;
            }

            // ---- write P (per-wave LDS region, swizzled) ----
            u16* Pw = &Ps[w][0];
            asm volatile("s_waitcnt lgkmcnt(0)" ::: "memory"); // prior PV reads done
#pragma unroll
            for (int nb = 0; nb < 4; nb++)
#pragma unroll
                for (int jj = 0; jj < 4; jj++) {
                    const int row = lg * 4 + jj;
                    const int e = row * 64 + nb * 16 + lr;
                    Pw[e ^ ((row & 7) << 3)] = f2bf(sf[nb][jj]);
                }
            asm volatile("s_waitcnt lgkmcnt(0)" ::: "memory");
            __builtin_amdgcn_sched_barrier(0);

            // ---- O += P V ----
#pragma unroll
            for (int kb2 = 0; kb2 < 2; ++kb2) {
                const int ep = lr * 64 + kb2 * 32 + lg * 8;
                bf16x8 pa = *(const bf16x8*)&Pw[ep ^ ((lr & 7) << 3)];
#pragma unroll
                for (int nb = 0; nb < 4; nb++) {
                    const int ev = (nb * 16 + lr) * 64 + kb2 * 32 + lg * 8;
                    bf16x8 vf = *(const bf16x8*)&Vs[cur][ev ^ ((lr & 7) << 3)];
                    acc[nb] = MFMA16(pa, vf, acc[nb]);
                }
            }
        }
        cur ^= 1;
    }

    // ---- epilogue: normalize, store to (B,T,1024) bf16 ----
    const int trow = r0 + lg * 4;
    u16* aob = ao + ((size_t)b * 2048) * 1024 + h * 64;
#pragma unroll
    for (int jj = 0; jj < 4; jj++) {
        const float inv = 1.0f / lsum[jj];
#pragma unroll
        for (int nb = 0; nb < 4; nb++)
            aob[(size_t)(trow + jj) * 1024 + nb * 16 + lr] = f2bf(acc[nb][jj] * inv);
    }
}

// ---------- launch ----------
extern "C" void kernel_launch(void* const* d_in, const int* in_sizes, int n_in,
                              void* d_out, int out_size, void* d_ws, size_t ws_size,
                              hipStream_t stream) {
    const float* x  = (const float*)d_in[0];
    const float* Wq = (const float*)d_in[2];
    const float* bq = (const float*)d_in[3];
    const float* Wk = (const float*)d_in[4];
    const float* bk = (const float*)d_in[5];
    const float* Wv = (const float*)d_in[6];
    const float* bv = (const float*)d_in[7];
    const float* Wo = (const float*)d_in[8];
    const float* bo = (const float*)d_in[9];
    float* out = (float*)d_out;

    const size_t MD = (size_t)8192 * 1024;
    u16* xb   = (u16*)d_ws;                 // x bf16; reused as vT after projections
    u16* wqkv = xb + MD;
    u16* wo   = wqkv + 3 * 1024 * 1024;
    u16* qw   = wo + 1024 * 1024;           // (B,H,T,64)
    u16* kw   = qw + MD;
    u16* vw   = kw + MD;                    // (B,H,T,64); reused as ao after transpose
    u16* vtw  = xb;                          // (B,H,64,T)
    u16* ao   = vw;                          // (B,T,1024)

    cvt_kernel<<<8192, 256, 0, stream>>>(x, xb, (int)(MD / 4));
    cvt_kernel<<<1024, 256, 0, stream>>>(Wq, wqkv, 262144);
    cvt_kernel<<<1024, 256, 0, stream>>>(Wk, wqkv + 1024 * 1024, 262144);
    cvt_kernel<<<1024, 256, 0, stream>>>(Wv, wqkv + 2 * 1024 * 1024, 262144);
    cvt_kernel<<<1024, 256, 0, stream>>>(Wo, wo, 262144);

    // QKV projection
    gemm_bt<0><<<dim3(24, 64), 256, 0, stream>>>(xb, wqkv, bq, bk, bv,
                                                 qw, kw, vw, nullptr);

    // transpose V: (B,H,T,64) -> (B,H,64,T)
    vtrans_kernel<<<dim3(32, 64), 256, 0, stream>>>(vw, vtw);

    // flash attention -> ao
    attn_kernel<<<1024, 512, 0, stream>>>(qw, kw, vtw, ao);

    // output projection
    gemm_bt<1><<<dim3(8, 64), 256, 0, stream>>>(ao, wo, bo, bo, bo,
                                                nullptr, nullptr, nullptr, out);
}